// Round 10
// baseline (182.851 us; speedup 1.0000x reference)
//
#include <hip/hip_runtime.h>

#define TT 512   // timesteps
#define ID 32    // input features
#define HD 64    // hidden
#define NTK 8    // tickers
#define RPB 4    // batch rows per block
#define ZPAD 80  // f16 elems per zbuf row (measured conflict-free)

typedef __attribute__((ext_vector_type(8))) _Float16 half8;
typedef __attribute__((ext_vector_type(2))) __fp16 fp16x2;
typedef __attribute__((ext_vector_type(4))) float f32x4;

#define L2E 1.44269504089f

__device__ __forceinline__ f32x4 MF(half8 a, half8 b, f32x4 c) {
    return __builtin_amdgcn_mfma_f32_16x16x32_f16(a, b, c, 0, 0, 0);
}

// two float4 -> half8 via 4x v_cvt_pkrtz_f16_f32
__device__ __forceinline__ half8 cvt8(float4 a, float4 b) {
    union { fp16x2 h2[4]; half8 h8; } u;
    u.h2[0] = __builtin_amdgcn_cvt_pkrtz(a.x, a.y);
    u.h2[1] = __builtin_amdgcn_cvt_pkrtz(a.z, a.w);
    u.h2[2] = __builtin_amdgcn_cvt_pkrtz(b.x, b.y);
    u.h2[3] = __builtin_amdgcn_cvt_pkrtz(b.z, b.w);
    return u.h8;
}

// 128 blocks x 256 threads (4 waves = 1/SIMD), 4 batch rows per block.
// gates(4 rows x 256) = z(4x96, M-rows 4x-dup) @ W^T, mfma_f32_16x16x32_f16.
// Lane (lq,l15) of wave wv activates the unique (i,f,g,o) quad of
// (batch row lq, hidden unit 16wv+l15) via fused-denominator algebra
// (5 exp2 + 3 rcp). x is read as f32 and converted inline with pkrtz —
// no pre-pass kernel (R8's cvt_x cost ~7us of pure serialization).
__global__ __launch_bounds__(256, 2) void lstm5(
    const float* __restrict__ x,       // (B, T, I)
    const float* __restrict__ w_ih,    // (4H, I)
    const float* __restrict__ w_hh,    // (4H, H)
    const float* __restrict__ b_ih,    // (4H)
    const float* __restrict__ b_hh,    // (4H)
    const float* __restrict__ w_fc,    // (NTK, H)
    const float* __restrict__ b_fc,    // (NTK)
    float* __restrict__ out)           // (B, NTK)
{
    const int tid = threadIdx.x;
    const int wv  = tid >> 6;          // wave 0..3
    const int l   = tid & 63;
    const int l15 = l & 15;
    const int lq  = l >> 4;            // k-chunk; = batch row this lane activates
    const int abr = l15 >> 2;          // batch row this lane's A-row supplies
    const int r0  = blockIdx.x * RPB;

    __shared__ __align__(16) _Float16 zbuf[2][RPB][ZPAD];   // double-buffered h

    // ---- loop-invariant B fragments (W^T) + bias C-in ----
    // B layout: col n = lane&15, k = (lane>>4)*8 + j. nt = gate type (i,f,g,o).
    half8 Bh0[4], Bh1[4], Bx[4];
    f32x4 biasC[4];
    #pragma unroll
    for (int nt = 0; nt < 4; ++nt) {
        const int n = nt * 64 + wv * 16 + l15;
        const float bias = b_ih[n] + b_hh[n];
        biasC[nt] = (f32x4){bias, bias, bias, bias};
        const float* ph = w_hh + n * HD + lq * 8;
        float4 p0 = ((const float4*)ph)[0], p1 = ((const float4*)ph)[1];
        Bh0[nt] = cvt8(p0, p1);
        p0 = ((const float4*)(ph + 32))[0]; p1 = ((const float4*)(ph + 32))[1];
        Bh1[nt] = cvt8(p0, p1);
        const float* px = w_ih + n * ID + lq * 8;
        p0 = ((const float4*)px)[0]; p1 = ((const float4*)px)[1];
        Bx[nt]  = cvt8(p0, p1);
    }

    zbuf[0][tid >> 6][tid & 63] = (_Float16)0.0f;   // h(0) = 0

    // x: lane supplies A-row abr -> x[r0+abr][t][lq*8 .. +8) as 2x float4
    const float* xq = x + ((size_t)(r0 + abr) * TT) * ID + lq * 8;

    float4 xa0 = ((const float4*)xq)[0],        xa1 = ((const float4*)(xq))[1];          // t=0
    float4 xb0 = ((const float4*)(xq + ID))[0], xb1 = ((const float4*)(xq + ID))[1];     // t=1
    float c_ = 0.0f;
    __syncthreads();

    // One step: z-reads issue -> inline x cvt + 4 x-MFMAs (cover z latency)
    // -> depth-2 x prefetch (off-chain) -> 8 h-MFMAs -> fused act -> h write.
#define STEP(RB, WB, XR0, XR1, TNEXT)                                               \
    {                                                                               \
        half8 z0 = *(const half8*)&zbuf[RB][abr][lq * 8];                           \
        half8 z1 = *(const half8*)&zbuf[RB][abr][32 + lq * 8];                      \
        half8 A2 = cvt8(XR0, XR1);                                                  \
        f32x4 aF = MF(A2, Bx[1], biasC[1]);                                         \
        f32x4 aI = MF(A2, Bx[0], biasC[0]);                                         \
        f32x4 aG = MF(A2, Bx[2], biasC[2]);                                         \
        f32x4 aO = MF(A2, Bx[3], biasC[3]);                                         \
        if ((TNEXT) < TT) {                                                         \
            const float* s_ = xq + (size_t)(TNEXT) * ID;                            \
            XR0 = ((const float4*)s_)[0];                                           \
            XR1 = ((const float4*)s_)[1];                                           \
        }                                                                           \
        aF = MF(z0, Bh0[1], aF);                                                    \
        aI = MF(z0, Bh0[0], aI);                                                    \
        aG = MF(z0, Bh0[2], aG);                                                    \
        aO = MF(z0, Bh0[3], aO);                                                    \
        aF = MF(z1, Bh1[1], aF);                                                    \
        aI = MF(z1, Bh1[0], aI);                                                    \
        aG = MF(z1, Bh1[2], aG);                                                    \
        aO = MF(z1, Bh1[3], aO);                                                    \
        const float ef = __builtin_amdgcn_exp2f(-L2E * aF[0]);                      \
        const float ei = __builtin_amdgcn_exp2f(-L2E * aI[0]);                      \
        const float eg = __builtin_amdgcn_exp2f(fminf(2.0f * L2E * aG[0], 60.0f));  \
        const float eo = __builtin_amdgcn_exp2f(-L2E * aO[0]);                      \
        const float rf  = __builtin_amdgcn_rcpf(1.0f + ef);                         \
        const float ti  = 1.0f + ei;                                                \
        const float rig = __builtin_amdgcn_rcpf(fmaf(eg, ti, ti));                  \
        c_ = fmaf(c_, rf, fmaf(eg, rig, -rig));                                     \
        const float ec = __builtin_amdgcn_exp2f(fminf(2.0f * L2E * c_, 60.0f));     \
        const float to = 1.0f + eo;                                                 \
        const float rh = __builtin_amdgcn_rcpf(fmaf(ec, to, to));                   \
        const float hh = fmaf(ec, rh, -rh);                                         \
        zbuf[WB][lq][wv * 16 + l15] = (_Float16)hh;                                 \
    }

    for (int t = 0; t < TT; t += 2) {
        STEP(0, 1, xa0, xa1, t + 2);    // even step: read buf0 -> write buf1
        __syncthreads();
        STEP(1, 0, xb0, xb1, t + 3);    // odd step:  read buf1 -> write buf0
        __syncthreads();
    }
#undef STEP

    // h(T) in zbuf[0]. FC head: 32 threads, one (row, ticker) each.
    if (tid < RPB * NTK) {
        const int rr = tid >> 3;
        const int tk = tid & 7;
        float a = b_fc[tk];
        const float* wf = w_fc + tk * HD;
        #pragma unroll
        for (int j = 0; j < HD; ++j)
            a = fmaf((float)zbuf[0][rr][j], wf[j], a);
        out[(r0 + rr) * NTK + tk] = a;
    }
}

extern "C" void kernel_launch(void* const* d_in, const int* in_sizes, int n_in,
                              void* d_out, int out_size, void* d_ws, size_t ws_size,
                              hipStream_t stream) {
    const float* x    = (const float*)d_in[0];
    const float* w_ih = (const float*)d_in[1];
    const float* w_hh = (const float*)d_in[2];
    const float* b_ih = (const float*)d_in[3];
    const float* b_hh = (const float*)d_in[4];
    const float* w_fc = (const float*)d_in[5];
    const float* b_fc = (const float*)d_in[6];
    float* out = (float*)d_out;

    const int nx = in_sizes[0];              // B*T*I
    const int B  = nx / (TT * ID);           // 512

    lstm5<<<dim3(B / RPB), dim3(256), 0, stream>>>(x, w_ih, w_hh, b_ih, b_hh,
                                                   w_fc, b_fc, out);
}

// Round 11
// 128.484 us; speedup vs baseline: 1.4231x; 1.4231x over previous
//
#include <hip/hip_runtime.h>

#define TT 512   // timesteps
#define ID 32    // input features
#define HD 64    // hidden
#define NTK 8    // tickers
#define RPB 4    // batch rows per block
#define ZPAD 80  // f16 elems per zbuf row (measured conflict-free)

typedef __attribute__((ext_vector_type(8))) _Float16 half8;
typedef __attribute__((ext_vector_type(2))) __fp16 fp16x2;
typedef __attribute__((ext_vector_type(4))) float f32x4;

#define L2E 1.44269504089f

__device__ __forceinline__ f32x4 MF(half8 a, half8 b, f32x4 c) {
    return __builtin_amdgcn_mfma_f32_16x16x32_f16(a, b, c, 0, 0, 0);
}

// two float4 -> half8 via 4x v_cvt_pkrtz_f16_f32 (f32 fallback path only)
__device__ __forceinline__ half8 cvt8(float4 a, float4 b) {
    union { fp16x2 h2[4]; half8 h8; } u;
    u.h2[0] = __builtin_amdgcn_cvt_pkrtz(a.x, a.y);
    u.h2[1] = __builtin_amdgcn_cvt_pkrtz(a.z, a.w);
    u.h2[2] = __builtin_amdgcn_cvt_pkrtz(b.x, b.y);
    u.h2[3] = __builtin_amdgcn_cvt_pkrtz(b.z, b.w);
    return u.h8;
}

// Pre-pass: x f32 -> f16 (one half8 per thread)  [known-good R8 x-path]
__global__ void cvt_x(const float* __restrict__ x, _Float16* __restrict__ xo, int n8) {
    int i = blockIdx.x * blockDim.x + threadIdx.x;
    if (i >= n8) return;
    const float4* p = (const float4*)x + 2 * (size_t)i;
    float4 a = p[0], b = p[1];
    half8 o = {(_Float16)a.x, (_Float16)a.y, (_Float16)a.z, (_Float16)a.w,
               (_Float16)b.x, (_Float16)b.y, (_Float16)b.z, (_Float16)b.w};
    *((half8*)xo + i) = o;
}

// 128 blocks x 256 threads (4 waves = 1/SIMD), 4 batch rows per block.
// GROUP-OF-4 xproj amortization: A-fragment M-rows packed as 4 rows x 4
// timesteps (row m=4r+s supplies x(row r, t+s)), so ONE set of 4 x-MFMAs
// per 4 steps yields lane (lq,l15)'s x-projection quad xp[s] = xproj(row lq,
// t+s, gate col 16wv+l15) in C-reg s. Each step s runs only 8 h-MFMAs with
// C-in = xp quads (A rows = z(row m>>2), all 4 dup), reads reg s
// (compile-time). Polluted C rows are never read. 12 -> 9 MFMA/wave/step.
// Fused activations (5 exp2 + 3 rcp) as R8.
template <bool XF16>
__global__ __launch_bounds__(256, 1) void lstm6(
    const float* __restrict__ x,       // (B, T, I) f32 (fallback)
    const _Float16* __restrict__ xf,   // (B, T, I) f16 (fast path)
    const float* __restrict__ w_ih,    // (4H, I)
    const float* __restrict__ w_hh,    // (4H, H)
    const float* __restrict__ b_ih,    // (4H)
    const float* __restrict__ b_hh,    // (4H)
    const float* __restrict__ w_fc,    // (NTK, H)
    const float* __restrict__ b_fc,    // (NTK)
    float* __restrict__ out)           // (B, NTK)
{
    const int tid = threadIdx.x;
    const int wv  = tid >> 6;          // wave 0..3
    const int l   = tid & 63;
    const int l15 = l & 15;
    const int lq  = l >> 4;            // k-chunk; = batch row this lane activates
    const int abr = l15 >> 2;          // batch row this lane's A-row supplies
    const int sst = l15 & 3;           // time slot this lane's A-row supplies (x packing)
    const int r0  = blockIdx.x * RPB;

    __shared__ __align__(16) _Float16 zbuf[2][RPB][ZPAD];   // double-buffered h

    // ---- loop-invariant B fragments (W^T, RNE casts) + bias C-in ----
    // B layout: col n = lane&15, k = (lane>>4)*8 + j. nt = gate type (i,f,g,o).
    half8 Bh0[4], Bh1[4], Bx[4];
    f32x4 biasC[4];
    #pragma unroll
    for (int nt = 0; nt < 4; ++nt) {
        const int n = nt * 64 + wv * 16 + l15;
        const float bias = b_ih[n] + b_hh[n];
        biasC[nt] = (f32x4){bias, bias, bias, bias};
        const float* ph = w_hh + n * HD + lq * 8;
        float4 p0 = ((const float4*)ph)[0], p1 = ((const float4*)ph)[1];
        Bh0[nt] = (half8){(_Float16)p0.x, (_Float16)p0.y, (_Float16)p0.z, (_Float16)p0.w,
                          (_Float16)p1.x, (_Float16)p1.y, (_Float16)p1.z, (_Float16)p1.w};
        p0 = ((const float4*)(ph + 32))[0]; p1 = ((const float4*)(ph + 32))[1];
        Bh1[nt] = (half8){(_Float16)p0.x, (_Float16)p0.y, (_Float16)p0.z, (_Float16)p0.w,
                          (_Float16)p1.x, (_Float16)p1.y, (_Float16)p1.z, (_Float16)p1.w};
        const float* px = w_ih + n * ID + lq * 8;
        p0 = ((const float4*)px)[0]; p1 = ((const float4*)px)[1];
        Bx[nt]  = (half8){(_Float16)p0.x, (_Float16)p0.y, (_Float16)p0.z, (_Float16)p0.w,
                          (_Float16)p1.x, (_Float16)p1.y, (_Float16)p1.z, (_Float16)p1.w};
    }

    zbuf[0][tid >> 6][tid & 63] = (_Float16)0.0f;   // h(0) = 0

    // x: lane loads x[r0+abr][t+sst][lq*8 .. +8) once per 4-step group
    const _Float16* xp16 = xf + ((size_t)(r0 + abr) * TT + sst) * ID + lq * 8;
    const float*    xp32 = x  + ((size_t)(r0 + abr) * TT + sst) * ID + lq * 8;

    auto ldx = [&](int tbase) -> half8 {
        if constexpr (XF16) {
            return *(const half8*)(xp16 + (size_t)tbase * ID);
        } else {
            const float* s_ = xp32 + (size_t)tbase * ID;
            return cvt8(((const float4*)s_)[0], ((const float4*)s_)[1]);
        }
    };

    half8 xcur = ldx(0);
    float c_ = 0.0f;
    __syncthreads();

    // One step: z ds_reads -> 8 h-MFMAs (C-in = xproj quads) -> fused act on
    // reg S (compile-time) -> h write. Barrier per step.
#define STEP(S, RB, WB)                                                             \
    {                                                                               \
        half8 z0 = *(const half8*)&zbuf[RB][abr][lq * 8];                           \
        half8 z1 = *(const half8*)&zbuf[RB][abr][32 + lq * 8];                      \
        f32x4 aF = MF(z0, Bh0[1], xpF);                                             \
        f32x4 aI = MF(z0, Bh0[0], xpI);                                             \
        f32x4 aG = MF(z0, Bh0[2], xpG);                                             \
        f32x4 aO = MF(z0, Bh0[3], xpO);                                             \
        aF = MF(z1, Bh1[1], aF);                                                    \
        aI = MF(z1, Bh1[0], aI);                                                    \
        aG = MF(z1, Bh1[2], aG);                                                    \
        aO = MF(z1, Bh1[3], aO);                                                    \
        const float ef = __builtin_amdgcn_exp2f(-L2E * aF[S]);                      \
        const float ei = __builtin_amdgcn_exp2f(-L2E * aI[S]);                      \
        const float eg = __builtin_amdgcn_exp2f(fminf(2.0f * L2E * aG[S], 60.0f));  \
        const float eo = __builtin_amdgcn_exp2f(-L2E * aO[S]);                      \
        const float rf  = __builtin_amdgcn_rcpf(1.0f + ef);                         \
        const float ti  = 1.0f + ei;                                                \
        const float rig = __builtin_amdgcn_rcpf(fmaf(eg, ti, ti));                  \
        c_ = fmaf(c_, rf, fmaf(eg, rig, -rig));                                     \
        const float ec = __builtin_amdgcn_exp2f(fminf(2.0f * L2E * c_, 60.0f));     \
        const float to = 1.0f + eo;                                                 \
        const float rh = __builtin_amdgcn_rcpf(fmaf(ec, to, to));                   \
        const float hh = fmaf(ec, rh, -rh);                                         \
        zbuf[WB][lq][wv * 16 + l15] = (_Float16)hh;                                 \
    }

    for (int t = 0; t < TT; t += 4) {
        // group-depth-1 x prefetch (clamped; ~4-step slack)
        const int tn = (t + 4 < TT) ? (t + 4) : t;
        half8 xnxt = ldx(tn);

        // 4 x-MFMAs for the whole group: xp[s] = xproj(row lq, t+s) in reg s
        f32x4 xpF = MF(xcur, Bx[1], biasC[1]);
        f32x4 xpI = MF(xcur, Bx[0], biasC[0]);
        f32x4 xpG = MF(xcur, Bx[2], biasC[2]);
        f32x4 xpO = MF(xcur, Bx[3], biasC[3]);

        STEP(0, 0, 1); __syncthreads();
        STEP(1, 1, 0); __syncthreads();
        STEP(2, 0, 1); __syncthreads();
        STEP(3, 1, 0); __syncthreads();

        xcur = xnxt;
    }
#undef STEP

    // h(T) in zbuf[0] (last step wrote buf 0). FC head: one (row,ticker)/thread.
    if (tid < RPB * NTK) {
        const int rr = tid >> 3;
        const int tk = tid & 7;
        float a = b_fc[tk];
        const float* wf = w_fc + tk * HD;
        #pragma unroll
        for (int j = 0; j < HD; ++j)
            a = fmaf((float)zbuf[0][rr][j], wf[j], a);
        out[(r0 + rr) * NTK + tk] = a;
    }
}

extern "C" void kernel_launch(void* const* d_in, const int* in_sizes, int n_in,
                              void* d_out, int out_size, void* d_ws, size_t ws_size,
                              hipStream_t stream) {
    const float* x    = (const float*)d_in[0];
    const float* w_ih = (const float*)d_in[1];
    const float* w_hh = (const float*)d_in[2];
    const float* b_ih = (const float*)d_in[3];
    const float* b_hh = (const float*)d_in[4];
    const float* w_fc = (const float*)d_in[5];
    const float* b_fc = (const float*)d_in[6];
    float* out = (float*)d_out;

    const int nx = in_sizes[0];              // B*T*I
    const int B  = nx / (TT * ID);           // 512
    const size_t need = (size_t)nx * sizeof(_Float16);

    if (ws_size >= need) {
        _Float16* xfw = (_Float16*)d_ws;
        const int n8 = nx / 8;
        cvt_x<<<dim3((n8 + 255) / 256), dim3(256), 0, stream>>>(x, xfw, n8);
        lstm6<true><<<dim3(B / RPB), dim3(256), 0, stream>>>(x, xfw, w_ih, w_hh,
                                                             b_ih, b_hh, w_fc, b_fc, out);
    } else {
        lstm6<false><<<dim3(B / RPB), dim3(256), 0, stream>>>(x, (const _Float16*)d_ws,
                                                              w_ih, w_hh, b_ih, b_hh,
                                                              w_fc, b_fc, out);
    }
}

// Round 12
// 127.446 us; speedup vs baseline: 1.4347x; 1.0081x over previous
//
#include <hip/hip_runtime.h>

#define TT 512   // timesteps
#define ID 32    // input features
#define HD 64    // hidden
#define NTK 8    // tickers
#define RPB 4    // batch rows per block
#define ZPAD 80  // f16 elems per zbuf row (measured conflict-free)

typedef __attribute__((ext_vector_type(8))) _Float16 half8;
typedef __attribute__((ext_vector_type(2))) __fp16 fp16x2;
typedef __attribute__((ext_vector_type(4))) float f32x4;

#define L2E 1.44269504089f

__device__ __forceinline__ f32x4 MF(half8 a, half8 b, f32x4 c) {
    return __builtin_amdgcn_mfma_f32_16x16x32_f16(a, b, c, 0, 0, 0);
}

// two float4 -> half8 via 4x v_cvt_pkrtz_f16_f32 (f32 fallback path only)
__device__ __forceinline__ half8 cvt8(float4 a, float4 b) {
    union { fp16x2 h2[4]; half8 h8; } u;
    u.h2[0] = __builtin_amdgcn_cvt_pkrtz(a.x, a.y);
    u.h2[1] = __builtin_amdgcn_cvt_pkrtz(a.z, a.w);
    u.h2[2] = __builtin_amdgcn_cvt_pkrtz(b.x, b.y);
    u.h2[3] = __builtin_amdgcn_cvt_pkrtz(b.z, b.w);
    return u.h8;
}

// Pre-pass: x f32 -> f16 (one half8 per thread)
__global__ void cvt_x(const float* __restrict__ x, _Float16* __restrict__ xo, int n8) {
    int i = blockIdx.x * blockDim.x + threadIdx.x;
    if (i >= n8) return;
    const float4* p = (const float4*)x + 2 * (size_t)i;
    float4 a = p[0], b = p[1];
    half8 o = {(_Float16)a.x, (_Float16)a.y, (_Float16)a.z, (_Float16)a.w,
               (_Float16)b.x, (_Float16)b.y, (_Float16)b.z, (_Float16)b.w};
    *((half8*)xo + i) = o;
}

// 128 blocks x 256 threads (4 waves = 1/SIMD), 4 batch rows per block.
// Group-of-4 xproj amortization (R11) + chain surgery:
//  - next-group x-MFMAs spread ONE PER STEP (8-step unrolled loop, A/B xp
//    register sets) so every step has a z-independent MFMA covering part of
//    the z ds_read latency;
//  - gate streams ordered O,F,I,G: eo/to/ef/rf/ei/ti computed while later
//    MFMAs issue; only eg->rig->c->ec->rh->hh (~60cy) after the last MFMA.
template <bool XF16>
__global__ __launch_bounds__(256, 1) void lstm7(
    const float* __restrict__ x,       // (B, T, I) f32 (fallback)
    const _Float16* __restrict__ xf,   // (B, T, I) f16 (fast path)
    const float* __restrict__ w_ih,    // (4H, I)
    const float* __restrict__ w_hh,    // (4H, H)
    const float* __restrict__ b_ih,    // (4H)
    const float* __restrict__ b_hh,    // (4H)
    const float* __restrict__ w_fc,    // (NTK, H)
    const float* __restrict__ b_fc,    // (NTK)
    float* __restrict__ out)           // (B, NTK)
{
    const int tid = threadIdx.x;
    const int wv  = tid >> 6;          // wave 0..3
    const int l   = tid & 63;
    const int l15 = l & 15;
    const int lq  = l >> 4;            // k-chunk; = batch row this lane activates
    const int abr = l15 >> 2;          // batch row this lane's A-row supplies
    const int sst = l15 & 3;           // time slot this lane's A-row supplies
    const int r0  = blockIdx.x * RPB;

    __shared__ __align__(16) _Float16 zbuf[2][RPB][ZPAD];   // double-buffered h

    // ---- loop-invariant B fragments (W^T) + bias C-in ----
    // B layout: col n = lane&15, k = (lane>>4)*8 + j. nt = gate type (i,f,g,o).
    half8 Bh0[4], Bh1[4], Bx[4];
    f32x4 biasC[4];
    #pragma unroll
    for (int nt = 0; nt < 4; ++nt) {
        const int n = nt * 64 + wv * 16 + l15;
        const float bias = b_ih[n] + b_hh[n];
        biasC[nt] = (f32x4){bias, bias, bias, bias};
        const float* ph = w_hh + n * HD + lq * 8;
        float4 p0 = ((const float4*)ph)[0], p1 = ((const float4*)ph)[1];
        Bh0[nt] = (half8){(_Float16)p0.x, (_Float16)p0.y, (_Float16)p0.z, (_Float16)p0.w,
                          (_Float16)p1.x, (_Float16)p1.y, (_Float16)p1.z, (_Float16)p1.w};
        p0 = ((const float4*)(ph + 32))[0]; p1 = ((const float4*)(ph + 32))[1];
        Bh1[nt] = (half8){(_Float16)p0.x, (_Float16)p0.y, (_Float16)p0.z, (_Float16)p0.w,
                          (_Float16)p1.x, (_Float16)p1.y, (_Float16)p1.z, (_Float16)p1.w};
        const float* px = w_ih + n * ID + lq * 8;
        p0 = ((const float4*)px)[0]; p1 = ((const float4*)px)[1];
        Bx[nt]  = (half8){(_Float16)p0.x, (_Float16)p0.y, (_Float16)p0.z, (_Float16)p0.w,
                          (_Float16)p1.x, (_Float16)p1.y, (_Float16)p1.z, (_Float16)p1.w};
    }

    zbuf[0][tid >> 6][tid & 63] = (_Float16)0.0f;   // h(0) = 0

    // x: lane loads x[r0+abr][t+sst][lq*8 .. +8) once per 4-step group
    const _Float16* xp16 = xf + ((size_t)(r0 + abr) * TT + sst) * ID + lq * 8;
    const float*    xp32 = x  + ((size_t)(r0 + abr) * TT + sst) * ID + lq * 8;

    auto ldx = [&](int tbase) -> half8 {
        if constexpr (XF16) {
            return *(const half8*)(xp16 + (size_t)tbase * ID);
        } else {
            const float* s_ = xp32 + (size_t)tbase * ID;
            return cvt8(((const float4*)s_)[0], ((const float4*)s_)[1]);
        }
    };

    // prologue: xpA for group t=0; xn0 feeds group t=4's build
    half8 xc = ldx(0);
    f32x4 xpA_O = MF(xc, Bx[3], biasC[3]);
    f32x4 xpA_F = MF(xc, Bx[1], biasC[1]);
    f32x4 xpA_I = MF(xc, Bx[0], biasC[0]);
    f32x4 xpA_G = MF(xc, Bx[2], biasC[2]);
    half8 xn0 = ldx(4);
    half8 xn1;
    f32x4 xpB_O, xpB_F, xpB_I, xpB_G;
    float c_ = 0.0f;
    __syncthreads();

    // One step: z ds_reads -> one next-group x-MFMA (z-independent, covers
    // latency) -> 8 h-MFMAs (streams O,F,I,G; z0 group then z1 group) ->
    // early eo/ef/ei -> short eg->c->h tail -> h write.
#define STEP(S, RB, WB, XPO, XPF, XPI, XPG, XBUILD)                                 \
    {                                                                               \
        half8 z0 = *(const half8*)&zbuf[RB][abr][lq * 8];                           \
        half8 z1 = *(const half8*)&zbuf[RB][abr][32 + lq * 8];                      \
        XBUILD;                                                                     \
        f32x4 aO = MF(z0, Bh0[3], XPO);                                             \
        f32x4 aF = MF(z0, Bh0[1], XPF);                                             \
        f32x4 aI = MF(z0, Bh0[0], XPI);                                             \
        f32x4 aG = MF(z0, Bh0[2], XPG);                                             \
        aO = MF(z1, Bh1[3], aO);                                                    \
        aF = MF(z1, Bh1[1], aF);                                                    \
        aI = MF(z1, Bh1[0], aI);                                                    \
        aG = MF(z1, Bh1[2], aG);                                                    \
        const float eo = __builtin_amdgcn_exp2f(-L2E * aO[S]);                      \
        const float ef = __builtin_amdgcn_exp2f(-L2E * aF[S]);                      \
        const float ei = __builtin_amdgcn_exp2f(-L2E * aI[S]);                      \
        const float to = 1.0f + eo;                                                 \
        const float rf = __builtin_amdgcn_rcpf(1.0f + ef);                          \
        const float ti = 1.0f + ei;                                                 \
        const float eg = __builtin_amdgcn_exp2f(fminf(2.0f * L2E * aG[S], 60.0f));  \
        const float rig = __builtin_amdgcn_rcpf(fmaf(eg, ti, ti));                  \
        c_ = fmaf(c_, rf, fmaf(eg, rig, -rig));                                     \
        const float ec = __builtin_amdgcn_exp2f(fminf(2.0f * L2E * c_, 60.0f));     \
        const float rh = __builtin_amdgcn_rcpf(fmaf(ec, to, to));                   \
        const float hh = fmaf(ec, rh, -rh);                                         \
        zbuf[WB][lq][wv * 16 + l15] = (_Float16)hh;                                 \
    }

    for (int t = 0; t < TT; t += 8) {
        const int tA = (t + 8  < TT) ? t + 8  : t;   // x for next iter's group A
        const int tB = (t + 12 < TT) ? t + 12 : t;   // x for next iter's group B
        // group A (t..t+3): uses xpA, builds xpB from xn0 = x(t+4)
        STEP(0, 0, 1, xpA_O, xpA_F, xpA_I, xpA_G,
             { xn1 = ldx(tA); xpB_O = MF(xn0, Bx[3], biasC[3]); });
        __syncthreads();
        STEP(1, 1, 0, xpA_O, xpA_F, xpA_I, xpA_G,
             { xpB_F = MF(xn0, Bx[1], biasC[1]); });
        __syncthreads();
        STEP(2, 0, 1, xpA_O, xpA_F, xpA_I, xpA_G,
             { xpB_I = MF(xn0, Bx[0], biasC[0]); });
        __syncthreads();
        STEP(3, 1, 0, xpA_O, xpA_F, xpA_I, xpA_G,
             { xpB_G = MF(xn0, Bx[2], biasC[2]); });
        __syncthreads();
        // group B (t+4..t+7): uses xpB, builds xpA from xn1 = x(t+8)
        STEP(0, 0, 1, xpB_O, xpB_F, xpB_I, xpB_G,
             { xn0 = ldx(tB); xpA_O = MF(xn1, Bx[3], biasC[3]); });
        __syncthreads();
        STEP(1, 1, 0, xpB_O, xpB_F, xpB_I, xpB_G,
             { xpA_F = MF(xn1, Bx[1], biasC[1]); });
        __syncthreads();
        STEP(2, 0, 1, xpB_O, xpB_F, xpB_I, xpB_G,
             { xpA_I = MF(xn1, Bx[0], biasC[0]); });
        __syncthreads();
        STEP(3, 1, 0, xpB_O, xpB_F, xpB_I, xpB_G,
             { xpA_G = MF(xn1, Bx[2], biasC[2]); });
        __syncthreads();
    }
#undef STEP

    // h(T) in zbuf[0] (last step writes buf 0). FC head: one (row,ticker)/thread.
    if (tid < RPB * NTK) {
        const int rr = tid >> 3;
        const int tk = tid & 7;
        float a = b_fc[tk];
        const float* wf = w_fc + tk * HD;
        #pragma unroll
        for (int j = 0; j < HD; ++j)
            a = fmaf((float)zbuf[0][rr][j], wf[j], a);
        out[(r0 + rr) * NTK + tk] = a;
    }
}

extern "C" void kernel_launch(void* const* d_in, const int* in_sizes, int n_in,
                              void* d_out, int out_size, void* d_ws, size_t ws_size,
                              hipStream_t stream) {
    const float* x    = (const float*)d_in[0];
    const float* w_ih = (const float*)d_in[1];
    const float* w_hh = (const float*)d_in[2];
    const float* b_ih = (const float*)d_in[3];
    const float* b_hh = (const float*)d_in[4];
    const float* w_fc = (const float*)d_in[5];
    const float* b_fc = (const float*)d_in[6];
    float* out = (float*)d_out;

    const int nx = in_sizes[0];              // B*T*I
    const int B  = nx / (TT * ID);           // 512
    const size_t need = (size_t)nx * sizeof(_Float16);

    if (ws_size >= need) {
        _Float16* xfw = (_Float16*)d_ws;
        const int n8 = nx / 8;
        cvt_x<<<dim3((n8 + 255) / 256), dim3(256), 0, stream>>>(x, xfw, n8);
        lstm7<true><<<dim3(B / RPB), dim3(256), 0, stream>>>(x, xfw, w_ih, w_hh,
                                                             b_ih, b_hh, w_fc, b_fc, out);
    } else {
        lstm7<false><<<dim3(B / RPB), dim3(256), 0, stream>>>(x, (const _Float16*)d_ws,
                                                              w_ih, w_hh, b_ih, b_hh,
                                                              w_fc, b_fc, out);
    }
}